// Round 1
// baseline (5632.368 us; speedup 1.0000x reference)
//
#include <hip/hip_runtime.h>
#include <stdint.h>

// MyVanillaRNN: B=64, T=512, INPUT=512, HIDDEN=1024
// out = concat( pre[B,T,H] (f32), h_final[B,H] (f32) )

typedef __attribute__((ext_vector_type(8))) short bf16x8;
typedef __attribute__((ext_vector_type(4))) float f32x4;

__device__ __forceinline__ uint32_t f2bf(float f) {
    union { float f; uint32_t u; } v; v.f = f;
    return (v.u + 0x7FFFu + ((v.u >> 16) & 1u)) >> 16;   // RNE
}
__device__ __forceinline__ uint32_t pack2bf(float a, float b) {
    return f2bf(a) | (f2bf(b) << 16);
}

// ---------------------------------------------------------------------------
// Phase 1: out[m][n] = sum_k x[m][k]*Wx[n][k] + bx[n] + bh[n]
// M=32768, N=1024, K=512.  128x128 tile, BK=64, 4 waves, bf16 MFMA.
// ---------------------------------------------------------------------------
__global__ __launch_bounds__(256) void xproj_gemm(
    const float* __restrict__ x, const float* __restrict__ Wx,
    const float* __restrict__ bx, const float* __restrict__ bh,
    float* __restrict__ out)
{
    __shared__ __align__(16) uint8_t Ab[128 * 128];  // 128 rows x 64 bf16, XOR-swizzled
    __shared__ __align__(16) uint8_t Bb[128 * 128];

    const int tid  = threadIdx.x;
    const int lane = tid & 63;
    const int wid  = tid >> 6;
    const int wm = wid >> 1, wn = wid & 1;
    const int m0 = (int)(blockIdx.x >> 3) * 128;
    const int n0 = (int)(blockIdx.x & 7) * 128;

    f32x4 acc[4][4];
    #pragma unroll
    for (int i = 0; i < 4; ++i)
        #pragma unroll
        for (int j = 0; j < 4; ++j) acc[i][j] = (f32x4){0.f, 0.f, 0.f, 0.f};

    const int sr = tid >> 4;          // staging row (+16 per pass)
    const int sk = (tid & 15) << 2;   // f32 col in row

    for (int k0 = 0; k0 < 512; k0 += 64) {
        __syncthreads();              // protect previous iter's reads
        #pragma unroll
        for (int p = 0; p < 8; ++p) {
            const int r = sr + p * 16;
            const float4 a = *(const float4*)(x  + (size_t)(m0 + r) * 512 + k0 + sk);
            const float4 b = *(const float4*)(Wx + (size_t)(n0 + r) * 512 + k0 + sk);
            const int byo = r * 128 + ((sk << 1) ^ ((r & 7) << 4));
            *(uint2*)(Ab + byo) = make_uint2(pack2bf(a.x, a.y), pack2bf(a.z, a.w));
            *(uint2*)(Bb + byo) = make_uint2(pack2bf(b.x, b.y), pack2bf(b.z, b.w));
        }
        __syncthreads();
        #pragma unroll
        for (int kt = 0; kt < 2; ++kt) {
            bf16x8 af[4], bfr[4];
            const int kb = (kt << 6) + ((lane >> 4) << 4);
            #pragma unroll
            for (int q = 0; q < 4; ++q) {
                const int ar = wm * 64 + q * 16 + (lane & 15);
                const int br = wn * 64 + q * 16 + (lane & 15);
                af[q]  = *(const bf16x8*)(Ab + ar * 128 + (kb ^ ((ar & 7) << 4)));
                bfr[q] = *(const bf16x8*)(Bb + br * 128 + (kb ^ ((br & 7) << 4)));
            }
            #pragma unroll
            for (int mt = 0; mt < 4; ++mt)
                #pragma unroll
                for (int nt = 0; nt < 4; ++nt)
                    acc[mt][nt] = __builtin_amdgcn_mfma_f32_16x16x32_bf16(
                        af[mt], bfr[nt], acc[mt][nt], 0, 0, 0);
        }
    }

    // epilogue: C layout col=lane&15 (N), row=(lane>>4)*4+i (M)
    #pragma unroll
    for (int nt = 0; nt < 4; ++nt) {
        const int n = n0 + wn * 64 + nt * 16 + (lane & 15);
        const float bias = bx[n] + bh[n];
        #pragma unroll
        for (int mt = 0; mt < 4; ++mt) {
            const int mb = m0 + wm * 64 + mt * 16 + ((lane >> 4) << 2);
            #pragma unroll
            for (int i = 0; i < 4; ++i)
                out[(size_t)(mb + i) * 1024 + n] = acc[mt][nt][i] + bias;
        }
    }
}

// ---------------------------------------------------------------------------
// Phase 2: persistent scan. 4 groups x 16 blocks; block = 512 thr (8 waves).
// Group g: batches [16g,16g+16). Block nb in group: H rows [64nb, 64nb+64).
// Wh slice lives in REGISTERS as MFMA B-frags (wave = coltile c x khalf).
// h exchanged via tagged words in d_ws: word = (bf16(h)<<16) | (state+1).
// State s lives in hbuf[s&1]; step t consumes s=t (tag t+1), produces s=t+1.
// Relaxed device-scope atomics only; value+tag share one word -> no fences.
// ---------------------------------------------------------------------------
__global__ __launch_bounds__(512) void rnn_scan(
    const float* __restrict__ h0, const float* __restrict__ Wh,
    float* __restrict__ out, float* __restrict__ hfin,
    uint32_t* __restrict__ hbuf)   // [2][64][1024]
{
    __shared__ __align__(16) uint8_t htile[16 * 2048]; // 16 batches x 1024 bf16, swizzled
    __shared__ __align__(16) float   pbuf[4 * 64 * 4]; // partial sums (khalf=1)

    const int tid  = threadIdx.x;
    const int gid  = blockIdx.x;
    const int g    = gid >> 4;         // group 0..3
    const int nb   = gid & 15;         // block in group
    const int gb0  = g * 16;           // batch base
    const int hb0  = nb * 64;          // H base
    const int lane = tid & 63;
    const int wid  = tid >> 6;         // 0..7
    const int c    = wid >> 1;         // coltile 0..3 (16 H cols each)
    const int kh   = wid & 1;          // K half (512 each)

    // --- load Wh B-fragments once: col = hb0+c*16+(lane&15), k in [kh*512,+512)
    bf16x8 whf[16];
    {
        const int col = hb0 + c * 16 + (lane & 15);
        const float* wp = Wh + (size_t)col * 1024 + kh * 512 + ((lane >> 4) << 3);
        #pragma unroll
        for (int kt = 0; kt < 16; ++kt) {
            const float4 w0 = *(const float4*)(wp + kt * 32);
            const float4 w1 = *(const float4*)(wp + kt * 32 + 4);
            bf16x8 f;
            f[0] = (short)f2bf(w0.x); f[1] = (short)f2bf(w0.y);
            f[2] = (short)f2bf(w0.z); f[3] = (short)f2bf(w0.w);
            f[4] = (short)f2bf(w1.x); f[5] = (short)f2bf(w1.y);
            f[6] = (short)f2bf(w1.z); f[7] = (short)f2bf(w1.w);
            whf[kt] = f;
        }
    }

    uint32_t* const hbE = hbuf;               // parity 0
    uint32_t* const hbO = hbuf + 64 * 1024;   // parity 1

    // --- publish initial state s=0 (tag 1, parity 0): my (batch x H) slice
    #pragma unroll
    for (int q = 0; q < 2; ++q) {
        const int li = (tid << 1) + q;        // 0..1023
        const int b   = gb0 + (li >> 6);
        const int hcl = hb0 + (li & 63);
        const float v = h0[(size_t)b * 1024 + hcl];
        __hip_atomic_store(&hbE[b * 1024 + hcl], (f2bf(v) << 16) | 1u,
                           __ATOMIC_RELAXED, __HIP_MEMORY_SCOPE_AGENT);
    }

    for (int t = 0; t < 512; ++t) {
        uint32_t* const src = (t & 1) ? hbO : hbE;
        const uint32_t exptag = (uint32_t)(t + 1);

        // --- phase A: gather h state (16 batches x 1024) into LDS
        uint32_t v[32];
        #pragma unroll
        for (int p = 0; p < 16; ++p) {
            const int idx = (gb0 + p) * 1024 + (tid << 1);
            v[2 * p]     = __hip_atomic_load(&src[idx],     __ATOMIC_RELAXED, __HIP_MEMORY_SCOPE_AGENT);
            v[2 * p + 1] = __hip_atomic_load(&src[idx + 1], __ATOMIC_RELAXED, __HIP_MEMORY_SCOPE_AGENT);
        }
        #pragma unroll
        for (int p = 0; p < 32; ++p) {
            const int idx = (gb0 + (p >> 1)) * 1024 + (tid << 1) + (p & 1);
            while ((v[p] & 0xFFFFu) != exptag) {
                __builtin_amdgcn_s_sleep(1);
                v[p] = __hip_atomic_load(&src[idx], __ATOMIC_RELAXED, __HIP_MEMORY_SCOPE_AGENT);
            }
        }
        #pragma unroll
        for (int p = 0; p < 16; ++p) {
            const uint32_t pk = (v[2 * p] >> 16) | (v[2 * p + 1] & 0xFFFF0000u);
            const int byo = p * 2048 + ((tid << 2) ^ ((p & 7) << 4));
            *(uint32_t*)(htile + byo) = pk;
        }
        __syncthreads();

        // --- phase B: acc = (Wh slice) . h  over this wave's K half
        f32x4 acc = (f32x4){0.f, 0.f, 0.f, 0.f};
        #pragma unroll
        for (int kt = 0; kt < 16; ++kt) {
            const int b  = lane & 15;
            const int kb = kh * 1024 + kt * 64 + ((lane >> 4) << 4);
            const bf16x8 a = *(const bf16x8*)(htile + b * 2048 + (kb ^ ((b & 7) << 4)));
            acc = __builtin_amdgcn_mfma_f32_16x16x32_bf16(a, whf[kt], acc, 0, 0, 0);
        }
        if (kh == 1)
            *(f32x4*)&pbuf[(c * 64 + lane) * 4] = acc;
        __syncthreads();

        // --- phase C: khalf 0 waves finalize: pre = xp + acc, publish tanh
        if (kh == 0) {
            const f32x4 part = *(const f32x4*)&pbuf[(c * 64 + lane) * 4];
            uint32_t* const dst = (t & 1) ? hbE : hbO;
            const uint32_t ntag = (uint32_t)(t + 2);
            const int hcl = hb0 + c * 16 + (lane & 15);
            #pragma unroll
            for (int i = 0; i < 4; ++i) {
                const int b = gb0 + ((lane >> 4) << 2) + i;
                const size_t oidx = ((size_t)b * 512 + t) * 1024 + hcl;
                const float pre = acc[i] + part[i] + out[oidx];
                out[oidx] = pre;
                const float hn = tanhf(pre);
                __hip_atomic_store(&dst[b * 1024 + hcl], (f2bf(hn) << 16) | ntag,
                                   __ATOMIC_RELAXED, __HIP_MEMORY_SCOPE_AGENT);
                if (t == 511) hfin[(size_t)b * 1024 + hcl] = hn;
            }
        }
    }
}

// ---------------------------------------------------------------------------
extern "C" void kernel_launch(void* const* d_in, const int* in_sizes, int n_in,
                              void* d_out, int out_size, void* d_ws, size_t ws_size,
                              hipStream_t stream) {
    const float* x   = (const float*)d_in[0];   // [64,512,512]
    const float* h0_ = (const float*)d_in[1];   // [64,1024]
    const float* Wx  = (const float*)d_in[2];   // [1024,512]
    const float* bx  = (const float*)d_in[3];   // [1024]
    const float* Wh  = (const float*)d_in[4];   // [1024,1024]
    const float* bh  = (const float*)d_in[5];   // [1024]
    float* out  = (float*)d_out;                         // [64,512,1024] pre
    float* hfin = out + (size_t)64 * 512 * 1024;         // [64,1024]
    uint32_t* hbuf = (uint32_t*)d_ws;                    // 2*64*1024 u32 = 512 KB

    // invalidate all tags (0xFFFF matches no step tag 1..513); also kills
    // any cross-replay/garbage tag collision.
    hipMemsetAsync(d_ws, 0xFF, (size_t)2 * 64 * 1024 * sizeof(uint32_t), stream);

    xproj_gemm<<<dim3(2048), dim3(256), 0, stream>>>(x, Wx, bx, bh, out);
    rnn_scan<<<dim3(64), dim3(512), 0, stream>>>(h0_, Wh, out, hfin, hbuf);
}

// Round 2
// 4369.532 us; speedup vs baseline: 1.2890x; 1.2890x over previous
//
#include <hip/hip_runtime.h>
#include <stdint.h>

// MyVanillaRNN: B=64, T=512, INPUT=512, HIDDEN=1024
// out = concat( pre[B,T,H] (f32), h_final[B,H] (f32) )

typedef __attribute__((ext_vector_type(8))) short bf16x8;
typedef __attribute__((ext_vector_type(4))) float f32x4;

__device__ __forceinline__ uint32_t f2bf(float f) {
    union { float f; uint32_t u; } v; v.f = f;
    return (v.u + 0x7FFFu + ((v.u >> 16) & 1u)) >> 16;   // RNE
}
__device__ __forceinline__ uint32_t pack2bf(float a, float b) {
    return f2bf(a) | (f2bf(b) << 16);
}
__device__ __forceinline__ float fast_tanh(float x) {
    const float xc = fminf(fmaxf(x, -15.f), 15.f);
    const float e  = __expf(2.f * xc);
    return (e - 1.f) * __builtin_amdgcn_rcpf(e + 1.f);
}

// ---------------------------------------------------------------------------
// Phase 1: out[m][n] = sum_k x[m][k]*Wx[n][k] + bx[n] + bh[n]
// M=32768, N=1024, K=512.  128x128 tile, BK=64, 4 waves, bf16 MFMA.
// ---------------------------------------------------------------------------
__global__ __launch_bounds__(256) void xproj_gemm(
    const float* __restrict__ x, const float* __restrict__ Wx,
    const float* __restrict__ bx, const float* __restrict__ bh,
    float* __restrict__ out)
{
    __shared__ __align__(16) uint8_t Ab[128 * 128];
    __shared__ __align__(16) uint8_t Bb[128 * 128];

    const int tid  = threadIdx.x;
    const int lane = tid & 63;
    const int wid  = tid >> 6;
    const int wm = wid >> 1, wn = wid & 1;
    const int m0 = (int)(blockIdx.x >> 3) * 128;
    const int n0 = (int)(blockIdx.x & 7) * 128;

    f32x4 acc[4][4];
    #pragma unroll
    for (int i = 0; i < 4; ++i)
        #pragma unroll
        for (int j = 0; j < 4; ++j) acc[i][j] = (f32x4){0.f, 0.f, 0.f, 0.f};

    const int sr = tid >> 4;
    const int sk = (tid & 15) << 2;

    for (int k0 = 0; k0 < 512; k0 += 64) {
        __syncthreads();
        #pragma unroll
        for (int p = 0; p < 8; ++p) {
            const int r = sr + p * 16;
            const float4 a = *(const float4*)(x  + (size_t)(m0 + r) * 512 + k0 + sk);
            const float4 b = *(const float4*)(Wx + (size_t)(n0 + r) * 512 + k0 + sk);
            const int byo = r * 128 + ((sk << 1) ^ ((r & 7) << 4));
            *(uint2*)(Ab + byo) = make_uint2(pack2bf(a.x, a.y), pack2bf(a.z, a.w));
            *(uint2*)(Bb + byo) = make_uint2(pack2bf(b.x, b.y), pack2bf(b.z, b.w));
        }
        __syncthreads();
        #pragma unroll
        for (int kt = 0; kt < 2; ++kt) {
            bf16x8 af[4], bfr[4];
            const int kb = (kt << 6) + ((lane >> 4) << 4);
            #pragma unroll
            for (int q = 0; q < 4; ++q) {
                const int ar = wm * 64 + q * 16 + (lane & 15);
                const int br = wn * 64 + q * 16 + (lane & 15);
                af[q]  = *(const bf16x8*)(Ab + ar * 128 + (kb ^ ((ar & 7) << 4)));
                bfr[q] = *(const bf16x8*)(Bb + br * 128 + (kb ^ ((br & 7) << 4)));
            }
            #pragma unroll
            for (int mt = 0; mt < 4; ++mt)
                #pragma unroll
                for (int nt = 0; nt < 4; ++nt)
                    acc[mt][nt] = __builtin_amdgcn_mfma_f32_16x16x32_bf16(
                        af[mt], bfr[nt], acc[mt][nt], 0, 0, 0);
        }
    }

    #pragma unroll
    for (int nt = 0; nt < 4; ++nt) {
        const int n = n0 + wn * 64 + nt * 16 + (lane & 15);
        const float bias = bx[n] + bh[n];
        #pragma unroll
        for (int mt = 0; mt < 4; ++mt) {
            const int mb = m0 + wm * 64 + mt * 16 + ((lane >> 4) << 2);
            #pragma unroll
            for (int i = 0; i < 4; ++i)
                out[(size_t)(mb + i) * 1024 + n] = acc[mt][nt][i] + bias;
        }
    }
}

// ---------------------------------------------------------------------------
// Phase 2: persistent scan. 4 groups x 8 blocks; block = 512 thr (8 waves).
// Group g: batches [16g,16g+16). Block nb: H cols [128nb, 128nb+128).
// Wave w: cols [128nb+16w, +16), FULL K=1024 -> no cross-wave reduction.
// h exchanged via tagged words in d_ws: word = (bf16(h)<<16) | (t+1).
// Poll is PARALLEL: every retry round re-issues all 32 loads back-to-back
// (one LLC latency per round), then checks -- round 1's serial re-poll was
// 32 sequential round-trips = 10.9us/step.
// ---------------------------------------------------------------------------
__global__ __launch_bounds__(512, 2) void rnn_scan(
    const float* __restrict__ h0, const float* __restrict__ Wh,
    float* __restrict__ out, float* __restrict__ hfin,
    uint32_t* __restrict__ hbuf)   // [2][64][1024]
{
    __shared__ __align__(16) uint8_t htile[16 * 2048]; // 16 batches x 1024 bf16, swizzled

    const int tid  = threadIdx.x;
    const int gid  = blockIdx.x;
    const int g    = gid >> 3;         // group 0..3
    const int nb   = gid & 7;          // block in group
    const int gb0  = g * 16;           // batch base
    const int hb0  = nb * 128;         // H base
    const int lane = tid & 63;
    const int wid  = tid >> 6;         // 0..7 (16-col tile)
    const int col  = hb0 + wid * 16 + (lane & 15);   // this lane's output H col

    // --- load Wh B-fragments once: col, full K. frag kt elem j <-> k=kt*32+(lane>>4)*8+j
    bf16x8 whf[32];
    {
        const float* wp = Wh + (size_t)col * 1024 + ((lane >> 4) << 3);
        #pragma unroll
        for (int kt = 0; kt < 32; ++kt) {
            const float4 w0 = *(const float4*)(wp + kt * 32);
            const float4 w1 = *(const float4*)(wp + kt * 32 + 4);
            bf16x8 f;
            f[0] = (short)f2bf(w0.x); f[1] = (short)f2bf(w0.y);
            f[2] = (short)f2bf(w0.z); f[3] = (short)f2bf(w0.w);
            f[4] = (short)f2bf(w1.x); f[5] = (short)f2bf(w1.y);
            f[6] = (short)f2bf(w1.z); f[7] = (short)f2bf(w1.w);
            whf[kt] = f;
        }
    }

    uint32_t* const hbE = hbuf;               // parity 0
    uint32_t* const hbO = hbuf + 64 * 1024;   // parity 1

    // --- publish initial state s=0 (tag 1, parity 0): my (16 batch x 128 col) slice
    #pragma unroll
    for (int q = 0; q < 4; ++q) {
        const int li  = (tid << 2) + q;       // 0..2047
        const int b   = gb0 + (li >> 7);
        const int hcl = hb0 + (li & 127);
        const float v = h0[(size_t)b * 1024 + hcl];
        __hip_atomic_store(&hbE[b * 1024 + hcl], (f2bf(v) << 16) | 1u,
                           __ATOMIC_RELAXED, __HIP_MEMORY_SCOPE_AGENT);
    }

    for (int t = 0; t < 512; ++t) {
        uint32_t* const src = (t & 1) ? hbO : hbE;
        const uint32_t exptag = (uint32_t)(t + 1);

        // --- prefetch xp for this step (completes under the poll)
        float xpv[4];
        #pragma unroll
        for (int i = 0; i < 4; ++i) {
            const int b = gb0 + ((lane >> 4) << 2) + i;
            xpv[i] = out[((size_t)b * 512 + t) * 1024 + col];
        }

        // --- phase A: parallel-poll h state (16 batches x 1024) -> LDS
        uint32_t v[32];
        #pragma unroll
        for (int p = 0; p < 16; ++p) {
            const int idx = (gb0 + p) * 1024 + (tid << 1);
            v[2 * p]     = __hip_atomic_load(&src[idx],     __ATOMIC_RELAXED, __HIP_MEMORY_SCOPE_AGENT);
            v[2 * p + 1] = __hip_atomic_load(&src[idx + 1], __ATOMIC_RELAXED, __HIP_MEMORY_SCOPE_AGENT);
        }
        while (true) {
            bool ok = true;
            #pragma unroll
            for (int p = 0; p < 32; ++p) ok &= ((v[p] & 0xFFFFu) == exptag);
            if (ok) break;
            __builtin_amdgcn_s_sleep(1);
            #pragma unroll
            for (int p = 0; p < 16; ++p) {
                const int idx = (gb0 + p) * 1024 + (tid << 1);
                v[2 * p]     = __hip_atomic_load(&src[idx],     __ATOMIC_RELAXED, __HIP_MEMORY_SCOPE_AGENT);
                v[2 * p + 1] = __hip_atomic_load(&src[idx + 1], __ATOMIC_RELAXED, __HIP_MEMORY_SCOPE_AGENT);
            }
        }
        #pragma unroll
        for (int p = 0; p < 16; ++p) {
            const uint32_t pk = (v[2 * p] >> 16) | (v[2 * p + 1] & 0xFFFF0000u);
            const int byo = p * 2048 + ((tid << 2) ^ ((p & 7) << 4));
            *(uint32_t*)(htile + byo) = pk;
        }
        __syncthreads();

        // --- phase B: acc = h . Wh[col]^T over full K, 4 interleaved chains
        f32x4 a0 = (f32x4){0.f,0.f,0.f,0.f}, a1 = a0, a2 = a0, a3 = a0;
        const int b_  = lane & 15;
        const int kbx = (lane >> 4) << 4;
        const int swz = (b_ & 7) << 4;
        #pragma unroll
        for (int kt = 0; kt < 32; kt += 4) {
            const bf16x8 f0 = *(const bf16x8*)(htile + b_ * 2048 + (((kt    ) * 64 + kbx) ^ swz));
            const bf16x8 f1 = *(const bf16x8*)(htile + b_ * 2048 + (((kt + 1) * 64 + kbx) ^ swz));
            const bf16x8 f2 = *(const bf16x8*)(htile + b_ * 2048 + (((kt + 2) * 64 + kbx) ^ swz));
            const bf16x8 f3 = *(const bf16x8*)(htile + b_ * 2048 + (((kt + 3) * 64 + kbx) ^ swz));
            a0 = __builtin_amdgcn_mfma_f32_16x16x32_bf16(f0, whf[kt    ], a0, 0, 0, 0);
            a1 = __builtin_amdgcn_mfma_f32_16x16x32_bf16(f1, whf[kt + 1], a1, 0, 0, 0);
            a2 = __builtin_amdgcn_mfma_f32_16x16x32_bf16(f2, whf[kt + 2], a2, 0, 0, 0);
            a3 = __builtin_amdgcn_mfma_f32_16x16x32_bf16(f3, whf[kt + 3], a3, 0, 0, 0);
        }

        // --- phase C: finalize pre, publish tanh
        uint32_t* const dst = (t & 1) ? hbE : hbO;
        const uint32_t ntag = (uint32_t)(t + 2);
        #pragma unroll
        for (int i = 0; i < 4; ++i) {
            const int b = gb0 + ((lane >> 4) << 2) + i;
            const size_t oidx = ((size_t)b * 512 + t) * 1024 + col;
            const float pre = ((a0[i] + a1[i]) + (a2[i] + a3[i])) + xpv[i];
            out[oidx] = pre;
            const float hn = fast_tanh(pre);
            if (t < 511) {
                __hip_atomic_store(&dst[b * 1024 + col], (f2bf(hn) << 16) | ntag,
                                   __ATOMIC_RELAXED, __HIP_MEMORY_SCOPE_AGENT);
            } else {
                hfin[(size_t)b * 1024 + col] = hn;
            }
        }
    }
}

// ---------------------------------------------------------------------------
extern "C" void kernel_launch(void* const* d_in, const int* in_sizes, int n_in,
                              void* d_out, int out_size, void* d_ws, size_t ws_size,
                              hipStream_t stream) {
    const float* x   = (const float*)d_in[0];   // [64,512,512]
    const float* h0_ = (const float*)d_in[1];   // [64,1024]
    const float* Wx  = (const float*)d_in[2];   // [1024,512]
    const float* bx  = (const float*)d_in[3];   // [1024]
    const float* Wh  = (const float*)d_in[4];   // [1024,1024]
    const float* bh  = (const float*)d_in[5];   // [1024]
    float* out  = (float*)d_out;                         // [64,512,1024] pre
    float* hfin = out + (size_t)64 * 512 * 1024;         // [64,1024]
    uint32_t* hbuf = (uint32_t*)d_ws;                    // 2*64*1024 u32 = 512 KB

    // invalidate all tags (0xFFFF matches no step tag 1..513)
    hipMemsetAsync(d_ws, 0xFF, (size_t)2 * 64 * 1024 * sizeof(uint32_t), stream);

    xproj_gemm<<<dim3(2048), dim3(256), 0, stream>>>(x, Wx, bx, bh, out);
    rnn_scan<<<dim3(32), dim3(512), 0, stream>>>(h0_, Wh, out, hfin, hbuf);
}

// Round 3
// 3700.423 us; speedup vs baseline: 1.5221x; 1.1808x over previous
//
#include <hip/hip_runtime.h>
#include <stdint.h>

// MyVanillaRNN: B=64, T=512, INPUT=512, HIDDEN=1024
// out = concat( pre[B,T,H] (f32), h_final[B,H] (f32) )

typedef __attribute__((ext_vector_type(8))) short bf16x8;
typedef __attribute__((ext_vector_type(4))) float f32x4;

__device__ __forceinline__ uint32_t f2bf(float f) {
    union { float f; uint32_t u; } v; v.f = f;
    return (v.u + 0x7FFFu + ((v.u >> 16) & 1u)) >> 16;   // RNE
}
__device__ __forceinline__ uint32_t pack2bf(float a, float b) {
    return f2bf(a) | (f2bf(b) << 16);
}
__device__ __forceinline__ float fast_tanh(float x) {
    const float xc = fminf(fmaxf(x, -15.f), 15.f);
    const float e  = __expf(2.f * xc);
    return (e - 1.f) * __builtin_amdgcn_rcpf(e + 1.f);
}
// L2-allowed load (bypasses L1 only). Same-XCD producer stores (write-through
// agent atomics) are visible here at L2 latency. NOT guaranteed fresh
// cross-XCD -> caller must fall back to agent-scope loads for liveness.
__device__ __forceinline__ uint32_t ld_sc0(const uint32_t* p) {
    uint32_t v;
    asm volatile("global_load_dword %0, %1, off sc0"
                 : "=v"(v) : "v"((uint64_t)(uintptr_t)p));
    return v;
}

// ---------------------------------------------------------------------------
// Phase 1: out[m][n] = sum_k x[m][k]*Wx[n][k] + bx[n] + bh[n]
// M=32768, N=1024, K=512.  128x128 tile, BK=64, 4 waves, bf16 MFMA.
// ---------------------------------------------------------------------------
__global__ __launch_bounds__(256) void xproj_gemm(
    const float* __restrict__ x, const float* __restrict__ Wx,
    const float* __restrict__ bx, const float* __restrict__ bh,
    float* __restrict__ out)
{
    __shared__ __align__(16) uint8_t Ab[128 * 128];
    __shared__ __align__(16) uint8_t Bb[128 * 128];

    const int tid  = threadIdx.x;
    const int lane = tid & 63;
    const int wid  = tid >> 6;
    const int wm = wid >> 1, wn = wid & 1;
    const int m0 = (int)(blockIdx.x >> 3) * 128;
    const int n0 = (int)(blockIdx.x & 7) * 128;

    f32x4 acc[4][4];
    #pragma unroll
    for (int i = 0; i < 4; ++i)
        #pragma unroll
        for (int j = 0; j < 4; ++j) acc[i][j] = (f32x4){0.f, 0.f, 0.f, 0.f};

    const int sr = tid >> 4;
    const int sk = (tid & 15) << 2;

    for (int k0 = 0; k0 < 512; k0 += 64) {
        __syncthreads();
        #pragma unroll
        for (int p = 0; p < 8; ++p) {
            const int r = sr + p * 16;
            const float4 a = *(const float4*)(x  + (size_t)(m0 + r) * 512 + k0 + sk);
            const float4 b = *(const float4*)(Wx + (size_t)(n0 + r) * 512 + k0 + sk);
            const int byo = r * 128 + ((sk << 1) ^ ((r & 7) << 4));
            *(uint2*)(Ab + byo) = make_uint2(pack2bf(a.x, a.y), pack2bf(a.z, a.w));
            *(uint2*)(Bb + byo) = make_uint2(pack2bf(b.x, b.y), pack2bf(b.z, b.w));
        }
        __syncthreads();
        #pragma unroll
        for (int kt = 0; kt < 2; ++kt) {
            bf16x8 af[4], bfr[4];
            const int kb = (kt << 6) + ((lane >> 4) << 4);
            #pragma unroll
            for (int q = 0; q < 4; ++q) {
                const int ar = wm * 64 + q * 16 + (lane & 15);
                const int br = wn * 64 + q * 16 + (lane & 15);
                af[q]  = *(const bf16x8*)(Ab + ar * 128 + (kb ^ ((ar & 7) << 4)));
                bfr[q] = *(const bf16x8*)(Bb + br * 128 + (kb ^ ((br & 7) << 4)));
            }
            #pragma unroll
            for (int mt = 0; mt < 4; ++mt)
                #pragma unroll
                for (int nt = 0; nt < 4; ++nt)
                    acc[mt][nt] = __builtin_amdgcn_mfma_f32_16x16x32_bf16(
                        af[mt], bfr[nt], acc[mt][nt], 0, 0, 0);
        }
    }

    #pragma unroll
    for (int nt = 0; nt < 4; ++nt) {
        const int n = n0 + wn * 64 + nt * 16 + (lane & 15);
        const float bias = bx[n] + bh[n];
        #pragma unroll
        for (int mt = 0; mt < 4; ++mt) {
            const int mb = m0 + wm * 64 + mt * 16 + ((lane >> 4) << 2);
            #pragma unroll
            for (int i = 0; i < 4; ++i)
                out[(size_t)(mb + i) * 1024 + n] = acc[mt][nt][i] + bias;
        }
    }
}

// ---------------------------------------------------------------------------
// Phase 2: persistent scan. 8 groups x 8 blocks; block = 512 thr (8 waves).
// Group g = blockIdx%8  -> all 8 blocks of a group land on XCD g under the
//   round-robin dispatch (perf heuristic only; correctness preserved by the
//   agent-scope fallback below).
// Group g: batches [8g, 8g+8). Block nb=blockIdx/8: H cols [128nb,+128).
// Wave w: cols [.. +16w, +16), FULL K=1024.
// h exchange: tagged words (bf16(h)<<16 | (t+1)) in d_ws.
//   publish = agent-scope relaxed atomic store (write-through; globally
//   visible at the fabric AND reflected in the local XCD L2).
//   poll    = sc0 loads (L2-hit fast path); after 8 failed rounds fall back
//   to agent-scope loads (always-fresh fabric path) for guaranteed progress.
// ---------------------------------------------------------------------------
__global__ __launch_bounds__(512, 2) void rnn_scan(
    const float* __restrict__ h0, const float* __restrict__ Wh,
    float* __restrict__ out, float* __restrict__ hfin,
    uint32_t* __restrict__ hbuf)   // [2][64][1024]
{
    __shared__ __align__(16) uint8_t htile[8 * 2048]; // 8 batches x 1024 bf16, swizzled

    const int tid  = threadIdx.x;
    const int gid  = blockIdx.x;
    const int g    = gid & 7;          // group == XCD id (heuristic)
    const int nb   = gid >> 3;         // block in group, 0..7
    const int gb0  = g * 8;            // batch base (8 batches)
    const int hb0  = nb * 128;         // H base
    const int lane = tid & 63;
    const int wid  = tid >> 6;         // 0..7 (16-col tile)
    const int col  = hb0 + wid * 16 + (lane & 15);   // this lane's output H col

    // --- load Wh B-fragments once: col, full K. frag kt elem j <-> k=kt*32+(lane>>4)*8+j
    bf16x8 whf[32];
    {
        const float* wp = Wh + (size_t)col * 1024 + ((lane >> 4) << 3);
        #pragma unroll
        for (int kt = 0; kt < 32; ++kt) {
            const float4 w0 = *(const float4*)(wp + kt * 32);
            const float4 w1 = *(const float4*)(wp + kt * 32 + 4);
            bf16x8 f;
            f[0] = (short)f2bf(w0.x); f[1] = (short)f2bf(w0.y);
            f[2] = (short)f2bf(w0.z); f[3] = (short)f2bf(w0.w);
            f[4] = (short)f2bf(w1.x); f[5] = (short)f2bf(w1.y);
            f[6] = (short)f2bf(w1.z); f[7] = (short)f2bf(w1.w);
            whf[kt] = f;
        }
    }

    uint32_t* const hbE = hbuf;               // parity 0
    uint32_t* const hbO = hbuf + 64 * 1024;   // parity 1

    // --- publish initial state s=0 (tag 1, parity 0): my (8 batch x 128 col) slice
    #pragma unroll
    for (int q = 0; q < 2; ++q) {
        const int li  = (tid << 1) + q;       // 0..1023
        const int b   = gb0 + (li >> 7);
        const int hcl = hb0 + (li & 127);
        const float v = h0[(size_t)b * 1024 + hcl];
        __hip_atomic_store(&hbE[b * 1024 + hcl], (f2bf(v) << 16) | 1u,
                           __ATOMIC_RELAXED, __HIP_MEMORY_SCOPE_AGENT);
    }

    for (int t = 0; t < 512; ++t) {
        uint32_t* const src = (t & 1) ? hbO : hbE;
        const uint32_t exptag = (uint32_t)(t + 1);

        // --- prefetch xp for this step (completes under the poll)
        const int rbase = ((lane >> 4) & 1) << 2;   // 0 or 4 (lanes>=32 duplicate)
        float xpv[4];
        #pragma unroll
        for (int i = 0; i < 4; ++i) {
            const int b = gb0 + rbase + i;
            xpv[i] = out[((size_t)b * 512 + t) * 1024 + col];
        }

        // --- phase A: poll h state (8 batches x 1024 cols) -- L2 fast path
        uint32_t v[16];
        #pragma unroll
        for (int p = 0; p < 8; ++p) {
            const int idx = (gb0 + p) * 1024 + (tid << 1);
            v[2 * p]     = ld_sc0(&src[idx]);
            v[2 * p + 1] = ld_sc0(&src[idx + 1]);
        }
        asm volatile("s_waitcnt vmcnt(0)" ::: "memory");
        __builtin_amdgcn_sched_barrier(0);

        int rounds = 0;
        while (true) {
            bool ok = true;
            #pragma unroll
            for (int p = 0; p < 16; ++p) ok &= ((v[p] & 0xFFFFu) == exptag);
            if (ok) break;
            ++rounds;
            __builtin_amdgcn_s_sleep(1);
            if (rounds <= 8) {
                #pragma unroll
                for (int p = 0; p < 8; ++p) {
                    const int idx = (gb0 + p) * 1024 + (tid << 1);
                    v[2 * p]     = ld_sc0(&src[idx]);
                    v[2 * p + 1] = ld_sc0(&src[idx + 1]);
                }
                asm volatile("s_waitcnt vmcnt(0)" ::: "memory");
                __builtin_amdgcn_sched_barrier(0);
            } else {
                // cross-XCD-safe fallback (fabric-coherent path)
                #pragma unroll
                for (int p = 0; p < 8; ++p) {
                    const int idx = (gb0 + p) * 1024 + (tid << 1);
                    v[2 * p]     = __hip_atomic_load(&src[idx],     __ATOMIC_RELAXED, __HIP_MEMORY_SCOPE_AGENT);
                    v[2 * p + 1] = __hip_atomic_load(&src[idx + 1], __ATOMIC_RELAXED, __HIP_MEMORY_SCOPE_AGENT);
                }
            }
        }

        #pragma unroll
        for (int p = 0; p < 8; ++p) {
            const uint32_t pk = (v[2 * p] >> 16) | (v[2 * p + 1] & 0xFFFF0000u);
            const int byo = p * 2048 + ((tid << 2) ^ (p << 4));
            *(uint32_t*)(htile + byo) = pk;
        }
        __syncthreads();
        // (no second barrier needed: a wave can only reach the next LDS write
        // after its poll succeeds, which requires ALL waves of this block to
        // have published step t -- which happens after their phase-B reads.)

        // --- phase B: acc = h . Wh[col]^T over full K, 4 interleaved chains
        // A-frag rows 8..15 duplicate batches 0..7 (lane&7); their C rows are
        // discarded.
        f32x4 a0 = (f32x4){0.f,0.f,0.f,0.f}, a1 = a0, a2 = a0, a3 = a0;
        const int b_  = lane & 7;
        const int kbx = (lane >> 4) << 4;
        const int swz = b_ << 4;
        #pragma unroll
        for (int kt = 0; kt < 32; kt += 4) {
            const bf16x8 f0 = *(const bf16x8*)(htile + b_ * 2048 + (((kt    ) * 64 + kbx) ^ swz));
            const bf16x8 f1 = *(const bf16x8*)(htile + b_ * 2048 + (((kt + 1) * 64 + kbx) ^ swz));
            const bf16x8 f2 = *(const bf16x8*)(htile + b_ * 2048 + (((kt + 2) * 64 + kbx) ^ swz));
            const bf16x8 f3 = *(const bf16x8*)(htile + b_ * 2048 + (((kt + 3) * 64 + kbx) ^ swz));
            a0 = __builtin_amdgcn_mfma_f32_16x16x32_bf16(f0, whf[kt    ], a0, 0, 0, 0);
            a1 = __builtin_amdgcn_mfma_f32_16x16x32_bf16(f1, whf[kt + 1], a1, 0, 0, 0);
            a2 = __builtin_amdgcn_mfma_f32_16x16x32_bf16(f2, whf[kt + 2], a2, 0, 0, 0);
            a3 = __builtin_amdgcn_mfma_f32_16x16x32_bf16(f3, whf[kt + 3], a3, 0, 0, 0);
        }

        // --- phase C: finalize pre; publish h FIRST (critical path), then out[]
        uint32_t* const dst = (t & 1) ? hbE : hbO;
        const uint32_t ntag = (uint32_t)(t + 2);
        float pre[4], hn[4];
        #pragma unroll
        for (int i = 0; i < 4; ++i) {
            pre[i] = ((a0[i] + a1[i]) + (a2[i] + a3[i])) + xpv[i];
            hn[i]  = fast_tanh(pre[i]);
        }
        if (lane < 32) {   // rows 0..7 valid; lanes>=32 hold duplicates
            if (t < 511) {
                #pragma unroll
                for (int i = 0; i < 4; ++i) {
                    const int b = gb0 + rbase + i;
                    __hip_atomic_store(&dst[b * 1024 + col], (f2bf(hn[i]) << 16) | ntag,
                                       __ATOMIC_RELAXED, __HIP_MEMORY_SCOPE_AGENT);
                }
            }
            #pragma unroll
            for (int i = 0; i < 4; ++i) {
                const int b = gb0 + rbase + i;
                out[((size_t)b * 512 + t) * 1024 + col] = pre[i];
                if (t == 511) hfin[(size_t)b * 1024 + col] = hn[i];
            }
        }
    }
}

// ---------------------------------------------------------------------------
extern "C" void kernel_launch(void* const* d_in, const int* in_sizes, int n_in,
                              void* d_out, int out_size, void* d_ws, size_t ws_size,
                              hipStream_t stream) {
    const float* x   = (const float*)d_in[0];   // [64,512,512]
    const float* h0_ = (const float*)d_in[1];   // [64,1024]
    const float* Wx  = (const float*)d_in[2];   // [1024,512]
    const float* bx  = (const float*)d_in[3];   // [1024]
    const float* Wh  = (const float*)d_in[4];   // [1024,1024]
    const float* bh  = (const float*)d_in[5];   // [1024]
    float* out  = (float*)d_out;                         // [64,512,1024] pre
    float* hfin = out + (size_t)64 * 512 * 1024;         // [64,1024]
    uint32_t* hbuf = (uint32_t*)d_ws;                    // 2*64*1024 u32 = 512 KB

    // invalidate all tags (0xFFFF matches no step tag 1..513)
    hipMemsetAsync(d_ws, 0xFF, (size_t)2 * 64 * 1024 * sizeof(uint32_t), stream);

    xproj_gemm<<<dim3(2048), dim3(256), 0, stream>>>(x, Wx, bx, bh, out);
    rnn_scan<<<dim3(64), dim3(512), 0, stream>>>(h0_, Wh, out, hfin, hbuf);
}